// Round 1
// baseline (130.153 us; speedup 1.0000x reference)
//
#include <hip/hip_runtime.h>

#define BB 4
#define NN 4096
#define GG 1024
#define CC 32
#define NSIG 4
#define GTILE 64
#define NTILE 64
#define PVALS 132   // 128 acc + 4 dens per (b,g)

// sigma = {0.01, 0.05, 0.1, 0.2} -> k = -0.5/sigma^2
#define K0 (-5000.0f)
#define K1 (-200.0f)
#define K2 (-50.0f)
#define K3 (-12.5f)

// Kernel 1: each block handles (b, 64 g's, one n-chunk). Lane = one g, holds
// acc[4 sigma][32 c] in registers. 4 waves split the n-tile 4-ways, block
// reduces across waves in LDS, wave 0 writes a partial (or final if direct).
__global__ __launch_bounds__(256) void gsc_partial_kernel(
    const float* __restrict__ px, const float* __restrict__ pf,
    const float* __restrict__ pm, const float* __restrict__ gx,
    float* __restrict__ partial, float* __restrict__ out0,
    float* __restrict__ out1, int nchunk, int direct)
{
    __shared__ float4 sbuf4[NTILE * CC / 4];  // 8 KB feat tile / reduce scratch
    __shared__ float sx[NTILE];
    __shared__ float sm[NTILE];
    float* sred = (float*)sbuf4;

    const int tid = threadIdx.x;
    const int w   = tid >> 6;      // wave 0..3
    const int gl  = tid & 63;      // lane = g within tile

    int bid = blockIdx.x;
    const int nc = bid % nchunk;
    bid /= nchunk;
    const int gt = bid % (GG / GTILE);
    const int b  = bid / (GG / GTILE);

    const int g = gt * GTILE + gl;
    const float gxv = gx[g];

    float acc[NSIG * CC];
#pragma unroll
    for (int i = 0; i < NSIG * CC; ++i) acc[i] = 0.0f;
    float dens[NSIG] = {0.0f, 0.0f, 0.0f, 0.0f};

    const int chunk   = NN / nchunk;
    const int n_begin = nc * chunk;

    const float* fbase = pf + (size_t)b * NN * CC;
    const float* xbase = px + (size_t)b * NN;
    const float* mbase = pm + (size_t)b * NN;

    for (int n0 = n_begin; n0 < n_begin + chunk; n0 += NTILE) {
        __syncthreads();
        // stage feat tile [64][32] = 512 float4, plus x and mask
        const float4* fsrc = (const float4*)(fbase + (size_t)n0 * CC);
        sbuf4[tid]       = fsrc[tid];
        sbuf4[tid + 256] = fsrc[tid + 256];
        if (tid < NTILE)                  sx[tid]         = xbase[n0 + tid];
        else if (tid < 2 * NTILE)         sm[tid - NTILE] = mbase[n0 + tid - NTILE];
        __syncthreads();

        const int nlo = w * (NTILE / 4);
        for (int k = 0; k < NTILE / 4; ++k) {
            const int n = nlo + k;
            const float dx = sx[n] - gxv;
            const float t  = dx * dx;
            const float m  = sm[n];
            const float w0 = __expf(K0 * t) * m;
            const float w1 = __expf(K1 * t) * m;
            const float w2 = __expf(K2 * t) * m;
            const float w3 = __expf(K3 * t) * m;
            dens[0] += w0; dens[1] += w1; dens[2] += w2; dens[3] += w3;
            const float4* fr = (const float4*)((const float*)sbuf4 + n * CC);
#pragma unroll
            for (int cq = 0; cq < CC / 4; ++cq) {
                const float4 f = fr[cq];
                acc[0 * CC + cq * 4 + 0] += w0 * f.x;
                acc[0 * CC + cq * 4 + 1] += w0 * f.y;
                acc[0 * CC + cq * 4 + 2] += w0 * f.z;
                acc[0 * CC + cq * 4 + 3] += w0 * f.w;
                acc[1 * CC + cq * 4 + 0] += w1 * f.x;
                acc[1 * CC + cq * 4 + 1] += w1 * f.y;
                acc[1 * CC + cq * 4 + 2] += w1 * f.z;
                acc[1 * CC + cq * 4 + 3] += w1 * f.w;
                acc[2 * CC + cq * 4 + 0] += w2 * f.x;
                acc[2 * CC + cq * 4 + 1] += w2 * f.y;
                acc[2 * CC + cq * 4 + 2] += w2 * f.z;
                acc[2 * CC + cq * 4 + 3] += w2 * f.w;
                acc[3 * CC + cq * 4 + 0] += w3 * f.x;
                acc[3 * CC + cq * 4 + 1] += w3 * f.y;
                acc[3 * CC + cq * 4 + 2] += w3 * f.z;
                acc[3 * CC + cq * 4 + 3] += w3 * f.w;
            }
        }
    }

    // cross-wave reduce into wave 0 (16 rounds of 8 acc values, then dens)
#pragma unroll
    for (int r = 0; r < 16; ++r) {
        __syncthreads();
#pragma unroll
        for (int j = 0; j < 8; ++j) sred[w * 512 + gl * 8 + j] = acc[r * 8 + j];
        __syncthreads();
        if (w == 0) {
#pragma unroll
            for (int j = 0; j < 8; ++j)
                acc[r * 8 + j] += sred[512 + gl * 8 + j] +
                                  sred[1024 + gl * 8 + j] +
                                  sred[1536 + gl * 8 + j];
        }
    }
    __syncthreads();
#pragma unroll
    for (int s = 0; s < NSIG; ++s) sred[w * 256 + gl * 4 + s] = dens[s];
    __syncthreads();
    if (w == 0) {
#pragma unroll
        for (int s = 0; s < NSIG; ++s)
            dens[s] += sred[256 + gl * 4 + s] + sred[512 + gl * 4 + s] +
                       sred[768 + gl * 4 + s];
    }

    if (w != 0) return;
    const size_t bg = (size_t)b * GG + g;

    if (!direct) {
        float* p = partial + ((size_t)nc * BB * GG + bg) * PVALS;
        float4* p4 = (float4*)p;
#pragma unroll
        for (int i = 0; i < NSIG * CC / 4; ++i)
            p4[i] = make_float4(acc[i * 4 + 0], acc[i * 4 + 1],
                                acc[i * 4 + 2], acc[i * 4 + 3]);
        p4[32] = make_float4(dens[0], dens[1], dens[2], dens[3]);
    } else {
#pragma unroll
        for (int s = 0; s < NSIG; ++s) {
            const float inv = 1.0f / fmaxf(dens[s], 1e-6f);
            float4* o4 = (float4*)(out0 + bg * (NSIG * CC) + s * CC);
#pragma unroll
            for (int cq = 0; cq < CC / 4; ++cq)
                o4[cq] = make_float4(acc[s * CC + cq * 4 + 0] * inv,
                                     acc[s * CC + cq * 4 + 1] * inv,
                                     acc[s * CC + cq * 4 + 2] * inv,
                                     acc[s * CC + cq * 4 + 3] * inv);
            out1[bg * NSIG + s] = dens[s];
        }
    }
}

// Kernel 2: sum partials over n-chunks, divide, write final outputs.
__global__ __launch_bounds__(128) void gsc_reduce_kernel(
    const float* __restrict__ partial, float* __restrict__ out0,
    float* __restrict__ out1, int nchunk)
{
    const size_t bg = blockIdx.x;
    const int v = threadIdx.x;   // 0..127 -> (s = v>>5, c = v&31)
    const int s = v >> 5;
    float num = 0.0f, dn = 0.0f;
    for (int nc = 0; nc < nchunk; ++nc) {
        const float* p = partial + ((size_t)nc * BB * GG + bg) * PVALS;
        num += p[v];
        dn  += p[128 + s];
    }
    out0[bg * 128 + v] = num / fmaxf(dn, 1e-6f);
    if (v < NSIG) {
        float d = 0.0f;
        for (int nc = 0; nc < nchunk; ++nc)
            d += partial[((size_t)nc * BB * GG + bg) * PVALS + 128 + v];
        out1[bg * NSIG + v] = d;
    }
}

extern "C" void kernel_launch(void* const* d_in, const int* in_sizes, int n_in,
                              void* d_out, int out_size, void* d_ws, size_t ws_size,
                              hipStream_t stream) {
    const float* px = (const float*)d_in[0];  // [B,N]
    const float* pf = (const float*)d_in[1];  // [B,N,C]
    const float* pm = (const float*)d_in[2];  // [B,N]
    const float* gx = (const float*)d_in[3];  // [G]
    float* out0 = (float*)d_out;                          // [B,G,4*C]
    float* out1 = out0 + (size_t)BB * GG * NSIG * CC;     // [B,G,4]

    const size_t per = (size_t)BB * GG * PVALS * sizeof(float);
    int nchunk = 1, direct = 1;
    if (8 * per <= ws_size)      { nchunk = 8; direct = 0; }
    else if (4 * per <= ws_size) { nchunk = 4; direct = 0; }
    else if (2 * per <= ws_size) { nchunk = 2; direct = 0; }
    else if (per <= ws_size)     { nchunk = 1; direct = 0; }

    const int grid1 = BB * (GG / GTILE) * nchunk;
    gsc_partial_kernel<<<dim3(grid1), dim3(256), 0, stream>>>(
        px, pf, pm, gx, (float*)d_ws, out0, out1, nchunk, direct);
    if (!direct)
        gsc_reduce_kernel<<<dim3(BB * GG), dim3(128), 0, stream>>>(
            (const float*)d_ws, out0, out1, nchunk);
}

// Round 2
// 92.186 us; speedup vs baseline: 1.4118x; 1.4118x over previous
//
#include <hip/hip_runtime.h>

#define BB 4
#define NN 4096
#define GG 1024
#define CC 32
#define NSIG 4
#define PVALS 132          // 128 acc + 4 dens per (b,g)
#define NT 128             // points per LDS tile
#define KS_PER_TILE (NT / 32)

// sigma = {0.01, 0.05, 0.1, 0.2} -> k = -0.5/sigma^2 = {-5000, -200, -50, -12.5}
// exp(k*t) = exp2(t * k/ln2). -200 = 4*-50 = 16*-12.5, so w(0.1)=w(0.2)^4,
// w(0.05)=w(0.1)^4 (repeated squaring); w(0.01) and w(0.2) via v_exp_f32.
#define C3 (-18.033688011112042f)   // -12.5/ln2  (sigma=0.2)
#define C0 (-7213.4752044448170f)   // -5000/ln2  (sigma=0.01)

typedef __attribute__((ext_vector_type(8))) short bf16x8;
typedef __attribute__((ext_vector_type(4))) float f32x4;

union frag_u { unsigned u[4]; bf16x8 v; };

// round-to-nearest f32->bf16 pair pack: (bits+0x8000)>>16, packed with v_perm
__device__ __forceinline__ unsigned pack_bf16(float lo, float hi) {
    unsigned a = __float_as_uint(lo) + 0x8000u;
    unsigned b = __float_as_uint(hi) + 0x8000u;
    return __builtin_amdgcn_perm(b, a, 0x07060302u);
}

// Block = 4 waves. Each wave owns a 16-g tile (block covers 64 g's), shares
// the LDS feat tile. Wave accumulates agg via mfma_f32_16x16x32_bf16:
//   A[m=g][k=n] = w_sigma (generated in-regs), B[k=n][n=c] = bf16(mask*feat),
//   plus a dens-MFMA with B = bf16(mask) broadcast over columns.
// feat is staged in LDS in MFMA-frag order: 16B per lane per (kstep, c-half),
// so B-frag loads are lane-linear ds_read_b128 (conflict-free).
__global__ __launch_bounds__(256) void gsc_mfma_kernel(
    const float* __restrict__ px, const float* __restrict__ pf,
    const float* __restrict__ pm, const float* __restrict__ gx,
    float* __restrict__ partial, float* __restrict__ out0,
    float* __restrict__ out1, int nchunk, int direct)
{
    __shared__ __align__(16) unsigned sfeat[KS_PER_TILE * 2 * 64 * 4]; // 8 KB
    __shared__ float sx[NT];
    __shared__ float sm[NT];

    const int tid = threadIdx.x;
    const int w   = tid >> 6;
    const int l   = tid & 63;
    const int q   = l >> 4;     // quad
    const int cl  = l & 15;

    int bid = blockIdx.x;
    const int nc = bid % nchunk; bid /= nchunk;
    const int gg = bid % (GG / 64);
    const int b  = bid / (GG / 64);
    const int gbase = gg * 64 + w * 16;

    // A-operand layout: A[m = lane&15][k = quad*8 + j]  -> lane's g = gbase+cl
    const float gxv = gx[gbase + cl];

    f32x4 acc[NSIG][2];
    f32x4 dacc[NSIG];
#pragma unroll
    for (int s = 0; s < NSIG; ++s) {
        acc[s][0] = (f32x4){0.f, 0.f, 0.f, 0.f};
        acc[s][1] = (f32x4){0.f, 0.f, 0.f, 0.f};
        dacc[s]   = (f32x4){0.f, 0.f, 0.f, 0.f};
    }

    const float* fb = pf + (size_t)b * NN * CC;
    const float* xb = px + (size_t)b * NN;
    const float* mb = pm + (size_t)b * NN;

    const int chunk   = NN / nchunk;
    const int n_begin = nc * chunk;

    const int sc   = tid & 31;   // staging: channel
    const int snp0 = tid >> 5;   // staging: n-pair base

    for (int n0 = n_begin; n0 < n_begin + chunk; n0 += NT) {
        __syncthreads();
        // ---- stage feat*mask as bf16 into frag-order LDS ----
        // element (n local, c) lives at frag slot:
        //   ks=n/32, q=(n%32)/8, j=n%8, h=c/16, lane=(q<<4)|(c&15), word j/2
#pragma unroll
        for (int it = 0; it < NT / 16; ++it) {
            const int np = snp0 + it * 8;    // n-pair 0..63
            const int nl = np * 2;
            const int ng = n0 + nl;
            const float m0 = mb[ng], m1 = mb[ng + 1];
            const float f0 = fb[(size_t)ng * CC + sc] * m0;
            const float f1 = fb[(size_t)(ng + 1) * CC + sc] * m1;
            const unsigned pk = pack_bf16(f0, f1);
            const int ks = nl >> 5, qq = (nl >> 3) & 3, j = nl & 7, h = sc >> 4;
            sfeat[(((ks * 2 + h) * 64) + ((qq << 4) | (sc & 15))) * 4 + (j >> 1)] = pk;
        }
        if (tid < NT)          sx[tid]      = xb[n0 + tid];
        else if (tid < 2 * NT) sm[tid - NT] = mb[n0 + tid - NT];
        __syncthreads();

#pragma unroll
        for (int ks = 0; ks < KS_PER_TILE; ++ks) {
            // lane's 8 k-points: ks*32 + q*8 + j  (quad-broadcast LDS reads)
            const float* xp = &sx[ks * 32 + q * 8];
            const float* mp = &sm[ks * 32 + q * 8];
            float t[8];
#pragma unroll
            for (int j = 0; j < 8; ++j) { const float dx = xp[j] - gxv; t[j] = dx * dx; }

            frag_u a0, a1, a2, a3, am;
#pragma unroll
            for (int j = 0; j < 8; j += 2) {
                const float w3a = __builtin_amdgcn_exp2f(t[j]     * C3);
                const float w3b = __builtin_amdgcn_exp2f(t[j + 1] * C3);
                float s;
                s = w3a * w3a; const float w2a = s * s;   // ^4 -> sigma 0.1
                s = w3b * w3b; const float w2b = s * s;
                s = w2a * w2a; const float w1a = s * s;   // ^4 -> sigma 0.05
                s = w2b * w2b; const float w1b = s * s;
                const float w0a = __builtin_amdgcn_exp2f(t[j]     * C0);
                const float w0b = __builtin_amdgcn_exp2f(t[j + 1] * C0);
                a3.u[j >> 1] = pack_bf16(w3a, w3b);
                a2.u[j >> 1] = pack_bf16(w2a, w2b);
                a1.u[j >> 1] = pack_bf16(w1a, w1b);
                a0.u[j >> 1] = pack_bf16(w0a, w0b);
                am.u[j >> 1] = pack_bf16(mp[j], mp[j + 1]);
            }

            const bf16x8* sfv = (const bf16x8*)sfeat;
            const bf16x8 bf0 = sfv[(ks * 2 + 0) * 64 + l];
            const bf16x8 bf1 = sfv[(ks * 2 + 1) * 64 + l];

            acc[0][0] = __builtin_amdgcn_mfma_f32_16x16x32_bf16(a0.v, bf0, acc[0][0], 0, 0, 0);
            acc[0][1] = __builtin_amdgcn_mfma_f32_16x16x32_bf16(a0.v, bf1, acc[0][1], 0, 0, 0);
            dacc[0]   = __builtin_amdgcn_mfma_f32_16x16x32_bf16(a0.v, am.v, dacc[0], 0, 0, 0);
            acc[1][0] = __builtin_amdgcn_mfma_f32_16x16x32_bf16(a1.v, bf0, acc[1][0], 0, 0, 0);
            acc[1][1] = __builtin_amdgcn_mfma_f32_16x16x32_bf16(a1.v, bf1, acc[1][1], 0, 0, 0);
            dacc[1]   = __builtin_amdgcn_mfma_f32_16x16x32_bf16(a1.v, am.v, dacc[1], 0, 0, 0);
            acc[2][0] = __builtin_amdgcn_mfma_f32_16x16x32_bf16(a2.v, bf0, acc[2][0], 0, 0, 0);
            acc[2][1] = __builtin_amdgcn_mfma_f32_16x16x32_bf16(a2.v, bf1, acc[2][1], 0, 0, 0);
            dacc[2]   = __builtin_amdgcn_mfma_f32_16x16x32_bf16(a2.v, am.v, dacc[2], 0, 0, 0);
            acc[3][0] = __builtin_amdgcn_mfma_f32_16x16x32_bf16(a3.v, bf0, acc[3][0], 0, 0, 0);
            acc[3][1] = __builtin_amdgcn_mfma_f32_16x16x32_bf16(a3.v, bf1, acc[3][1], 0, 0, 0);
            dacc[3]   = __builtin_amdgcn_mfma_f32_16x16x32_bf16(a3.v, am.v, dacc[3], 0, 0, 0);
        }
    }

    // ---- epilogue. C/D layout: col(c) = lane&15 (+16h), row(g) = quad*4+reg
    if (!direct) {
        float* p = partial + ((size_t)nc * BB * GG + (size_t)b * GG + gbase) * PVALS;
#pragma unroll
        for (int s = 0; s < NSIG; ++s)
#pragma unroll
            for (int h = 0; h < 2; ++h)
#pragma unroll
                for (int r = 0; r < 4; ++r)
                    p[(q * 4 + r) * PVALS + s * 32 + h * 16 + cl] = acc[s][h][r];
        if (cl == 0) {
#pragma unroll
            for (int s = 0; s < NSIG; ++s)
#pragma unroll
                for (int r = 0; r < 4; ++r)
                    p[(q * 4 + r) * PVALS + 128 + s] = dacc[s][r];
        }
    } else {
        float* o0 = out0 + ((size_t)b * GG + gbase) * (NSIG * CC);
        float* o1 = out1 + ((size_t)b * GG + gbase) * NSIG;
#pragma unroll
        for (int s = 0; s < NSIG; ++s)
#pragma unroll
            for (int r = 0; r < 4; ++r) {
                const float d = dacc[s][r];
                const float inv = 1.0f / fmaxf(d, 1e-6f);
#pragma unroll
                for (int h = 0; h < 2; ++h)
                    o0[(q * 4 + r) * (NSIG * CC) + s * CC + h * 16 + cl] = acc[s][h][r] * inv;
                if (cl == 0) o1[(q * 4 + r) * NSIG + s] = d;
            }
    }
}

// Kernel 2: sum partials over n-chunks, divide, write final outputs.
__global__ __launch_bounds__(128) void gsc_reduce_kernel(
    const float* __restrict__ partial, float* __restrict__ out0,
    float* __restrict__ out1, int nchunk)
{
    const size_t bg = blockIdx.x;
    const int v = threadIdx.x;   // 0..127 -> (s = v>>5, c = v&31)
    const int s = v >> 5;
    float num = 0.0f, dn = 0.0f;
    for (int nc = 0; nc < nchunk; ++nc) {
        const float* p = partial + ((size_t)nc * BB * GG + bg) * PVALS;
        num += p[v];
        dn  += p[128 + s];
    }
    out0[bg * 128 + v] = num / fmaxf(dn, 1e-6f);
    if (v < NSIG) {
        float d = 0.0f;
        for (int nc = 0; nc < nchunk; ++nc)
            d += partial[((size_t)nc * BB * GG + bg) * PVALS + 128 + v];
        out1[bg * NSIG + v] = d;
    }
}

extern "C" void kernel_launch(void* const* d_in, const int* in_sizes, int n_in,
                              void* d_out, int out_size, void* d_ws, size_t ws_size,
                              hipStream_t stream) {
    const float* px = (const float*)d_in[0];  // [B,N]
    const float* pf = (const float*)d_in[1];  // [B,N,C]
    const float* pm = (const float*)d_in[2];  // [B,N]
    const float* gx = (const float*)d_in[3];  // [G]
    float* out0 = (float*)d_out;                          // [B,G,4*C]
    float* out1 = out0 + (size_t)BB * GG * NSIG * CC;     // [B,G,4]

    const size_t per = (size_t)BB * GG * PVALS * sizeof(float);
    int nchunk = 1, direct = 1;
    if (8 * per <= ws_size)      { nchunk = 8; direct = 0; }
    else if (4 * per <= ws_size) { nchunk = 4; direct = 0; }
    else if (2 * per <= ws_size) { nchunk = 2; direct = 0; }
    else if (per <= ws_size)     { nchunk = 1; direct = 0; }

    const int grid1 = BB * (GG / 64) * nchunk;
    gsc_mfma_kernel<<<dim3(grid1), dim3(256), 0, stream>>>(
        px, pf, pm, gx, (float*)d_ws, out0, out1, nchunk, direct);
    if (!direct)
        gsc_reduce_kernel<<<dim3(BB * GG), dim3(128), 0, stream>>>(
            (const float*)d_ws, out0, out1, nchunk);
}

// Round 3
// 88.143 us; speedup vs baseline: 1.4766x; 1.0459x over previous
//
#include <hip/hip_runtime.h>

#define BB 4
#define NN 4096
#define GG 1024
#define CC 32
#define NSIG 4
#define PVALS 132          // 128 acc + 4 dens per (b,g)
#define NT 128             // points per LDS tile
#define KS_PER_TILE (NT / 32)

// sigma = {0.01, 0.05, 0.1, 0.2} -> k = -0.5/sigma^2 = {-5000, -200, -50, -12.5}
// w(0.1)=w(0.2)^4, w(0.05)=w(0.1)^4 (repeated squaring); exp2 only for 0.2, 0.01.
#define C3 (-18.033688011112042f)   // -12.5/ln2  (sigma=0.2)
#define C0 (-7213.4752044448170f)   // -5000/ln2  (sigma=0.01)

typedef __attribute__((ext_vector_type(8))) short bf16x8;
typedef __attribute__((ext_vector_type(4))) float f32x4;

union frag_u { unsigned u[4]; bf16x8 v; };

__device__ __forceinline__ unsigned pack_bf16(float lo, float hi) {
    unsigned a = __float_as_uint(lo) + 0x8000u;
    unsigned b = __float_as_uint(hi) + 0x8000u;
    return __builtin_amdgcn_perm(b, a, 0x07060302u);
}

#define AS1 __attribute__((address_space(1)))
#define AS3 __attribute__((address_space(3)))
__device__ __forceinline__ void ld_lds16(const void* g, void* l) {
    __builtin_amdgcn_global_load_lds((const AS1 unsigned*)g, (AS3 unsigned*)l, 16, 0, 0);
}
__device__ __forceinline__ void ld_lds4(const void* g, void* l) {
    __builtin_amdgcn_global_load_lds((const AS1 unsigned*)g, (AS3 unsigned*)l, 4, 0, 0);
}

// ---- prep: feat*mask -> bf16 in MFMA-B-frag order; mask -> linear bf16 ----
// frag layout: element (b, n, c) -> row R=(b*(NN/32)+n/32)*2 + c/16 (1024 B rows),
// lane = ((n%32)/8)*16 + c%16, word = (n%8)/2, half = n%2.
__global__ __launch_bounds__(256) void gsc_prep_kernel(
    const float* __restrict__ pf, const float* __restrict__ pm,
    unsigned* __restrict__ fragw, unsigned* __restrict__ maskw)
{
    const int gid  = blockIdx.x * 256 + threadIdx.x;
    const int c    = gid & 31;
    const int rest = gid >> 5;
    const int np   = rest & (NN / 2 - 1);
    const int b    = rest >> 11;
    const int nl   = np * 2;
    const size_t ng = (size_t)b * NN + nl;
    const float m0 = pm[ng], m1 = pm[ng + 1];
    const float f0 = pf[ng * CC + c] * m0;
    const float f1 = pf[(ng + 1) * CC + c] * m1;
    const int ks = nl >> 5, qq = (nl >> 3) & 3, j = nl & 7, h = c >> 4;
    fragw[(((size_t)b * (NN / 32) + ks) * 2 + h) * 256 +
          (((qq << 4) | (c & 15)) << 2) + (j >> 1)] = pack_bf16(f0, f1);
    if (c == 0) maskw[ng >> 1] = pack_bf16(m0, m1);
}

struct __align__(16) TileBuf {
    unsigned feat[8 * 256];   // 8 frag rows x 1024 B
    float    x[NT];           // 512 B
    unsigned mask[64];        // 128 bf16
};

// ---- main: block = 4 waves, each wave owns 16 g's; async double-buffered
// staging via global_load_lds; A (weights) generated in-registers.
__global__ __launch_bounds__(256) void gsc_mfma_kernel(
    const float* __restrict__ px, const unsigned* __restrict__ fragw,
    const unsigned* __restrict__ maskw, const float* __restrict__ gx,
    float* __restrict__ partial, float* __restrict__ out0,
    float* __restrict__ out1, int nchunk, int direct)
{
    __shared__ TileBuf tiles[2];

    const int tid = threadIdx.x;
    const int w   = tid >> 6;
    const int l   = tid & 63;
    const int q   = l >> 4;
    const int cl  = l & 15;

    int bid = blockIdx.x;
    const int nc = bid % nchunk; bid /= nchunk;
    const int gg = bid % (GG / 64);
    const int b  = bid / (GG / 64);
    const int gbase = gg * 64 + w * 16;

    const float gxv = gx[gbase + cl];

    f32x4 acc[NSIG][2];
    f32x4 dacc[NSIG];
#pragma unroll
    for (int s = 0; s < NSIG; ++s) {
        acc[s][0] = (f32x4){0.f, 0.f, 0.f, 0.f};
        acc[s][1] = (f32x4){0.f, 0.f, 0.f, 0.f};
        dacc[s]   = (f32x4){0.f, 0.f, 0.f, 0.f};
    }

    const int chunk   = NN / nchunk;
    const int n_begin = nc * chunk;
    const int T       = chunk / NT;

    auto stage = [&](int t, int bufi) {
        TileBuf* tb = &tiles[bufi];
        const int n0 = n_begin + t * NT;
        // feat rows for this tile start at R = b*256 + n0/16 (1024 B each)
        const char* src = (const char*)fragw +
                          ((size_t)b * 256 + (n0 >> 4) + 2 * w) * 1024 + (size_t)l * 16;
        ld_lds16(src,        &tb->feat[(2 * w) * 256]);
        ld_lds16(src + 1024, &tb->feat[(2 * w + 1) * 256]);
        if (w == 0) {
            const float* xs = px + (size_t)b * NN + n0;
            ld_lds4(xs + l,      &tb->x[0]);
            ld_lds4(xs + 64 + l, &tb->x[64]);
        } else if (w == 1) {
            ld_lds4(maskw + (((size_t)b * NN + n0) >> 1) + l, &tb->mask[0]);
        }
    };

    auto compute = [&](int bufi) {
        TileBuf* tb = &tiles[bufi];
#pragma unroll
        for (int ks = 0; ks < KS_PER_TILE; ++ks) {
            const float4 xa = *(const float4*)&tb->x[ks * 32 + q * 8];
            const float4 xb = *(const float4*)&tb->x[ks * 32 + q * 8 + 4];
            float tt[8];
            float d;
            d = xa.x - gxv; tt[0] = d * d;
            d = xa.y - gxv; tt[1] = d * d;
            d = xa.z - gxv; tt[2] = d * d;
            d = xa.w - gxv; tt[3] = d * d;
            d = xb.x - gxv; tt[4] = d * d;
            d = xb.y - gxv; tt[5] = d * d;
            d = xb.z - gxv; tt[6] = d * d;
            d = xb.w - gxv; tt[7] = d * d;

            frag_u a0, a1, a2, a3;
#pragma unroll
            for (int j = 0; j < 8; j += 2) {
                const float w3a = __builtin_amdgcn_exp2f(tt[j]     * C3);
                const float w3b = __builtin_amdgcn_exp2f(tt[j + 1] * C3);
                float s;
                s = w3a * w3a; const float w2a = s * s;   // ^4 -> sigma 0.1
                s = w3b * w3b; const float w2b = s * s;
                s = w2a * w2a; const float w1a = s * s;   // ^4 -> sigma 0.05
                s = w2b * w2b; const float w1b = s * s;
                const float w0a = __builtin_amdgcn_exp2f(tt[j]     * C0);
                const float w0b = __builtin_amdgcn_exp2f(tt[j + 1] * C0);
                a3.u[j >> 1] = pack_bf16(w3a, w3b);
                a2.u[j >> 1] = pack_bf16(w2a, w2b);
                a1.u[j >> 1] = pack_bf16(w1a, w1b);
                a0.u[j >> 1] = pack_bf16(w0a, w0b);
            }

            const bf16x8 amv = *(const bf16x8*)((const char*)tb->mask + ks * 64 + q * 16);
            const bf16x8 bf0 = *(const bf16x8*)&tb->feat[(ks * 2 + 0) * 256 + l * 4];
            const bf16x8 bf1 = *(const bf16x8*)&tb->feat[(ks * 2 + 1) * 256 + l * 4];

            acc[0][0] = __builtin_amdgcn_mfma_f32_16x16x32_bf16(a0.v, bf0, acc[0][0], 0, 0, 0);
            acc[0][1] = __builtin_amdgcn_mfma_f32_16x16x32_bf16(a0.v, bf1, acc[0][1], 0, 0, 0);
            dacc[0]   = __builtin_amdgcn_mfma_f32_16x16x32_bf16(a0.v, amv, dacc[0], 0, 0, 0);
            acc[1][0] = __builtin_amdgcn_mfma_f32_16x16x32_bf16(a1.v, bf0, acc[1][0], 0, 0, 0);
            acc[1][1] = __builtin_amdgcn_mfma_f32_16x16x32_bf16(a1.v, bf1, acc[1][1], 0, 0, 0);
            dacc[1]   = __builtin_amdgcn_mfma_f32_16x16x32_bf16(a1.v, amv, dacc[1], 0, 0, 0);
            acc[2][0] = __builtin_amdgcn_mfma_f32_16x16x32_bf16(a2.v, bf0, acc[2][0], 0, 0, 0);
            acc[2][1] = __builtin_amdgcn_mfma_f32_16x16x32_bf16(a2.v, bf1, acc[2][1], 0, 0, 0);
            dacc[2]   = __builtin_amdgcn_mfma_f32_16x16x32_bf16(a2.v, amv, dacc[2], 0, 0, 0);
            acc[3][0] = __builtin_amdgcn_mfma_f32_16x16x32_bf16(a3.v, bf0, acc[3][0], 0, 0, 0);
            acc[3][1] = __builtin_amdgcn_mfma_f32_16x16x32_bf16(a3.v, bf1, acc[3][1], 0, 0, 0);
            dacc[3]   = __builtin_amdgcn_mfma_f32_16x16x32_bf16(a3.v, amv, dacc[3], 0, 0, 0);
        }
    };

    stage(0, 0);
#pragma unroll 1
    for (int t = 0; t < T; ++t) {
        __syncthreads();                       // drains tile t's loads
        if (t + 1 < T) stage(t + 1, (t + 1) & 1);  // fly during compute(t)
        compute(t & 1);
    }

    // ---- epilogue. C/D layout: col(c) = lane&15 (+16h), row(g) = quad*4+reg
    if (!direct) {
        float* p = partial + ((size_t)nc * BB * GG + (size_t)b * GG + gbase) * PVALS;
#pragma unroll
        for (int s = 0; s < NSIG; ++s)
#pragma unroll
            for (int h = 0; h < 2; ++h)
#pragma unroll
                for (int r = 0; r < 4; ++r)
                    p[(q * 4 + r) * PVALS + s * 32 + h * 16 + cl] = acc[s][h][r];
        if (cl == 0) {
#pragma unroll
            for (int s = 0; s < NSIG; ++s)
#pragma unroll
                for (int r = 0; r < 4; ++r)
                    p[(q * 4 + r) * PVALS + 128 + s] = dacc[s][r];
        }
    } else {
        float* o0 = out0 + ((size_t)b * GG + gbase) * (NSIG * CC);
        float* o1 = out1 + ((size_t)b * GG + gbase) * NSIG;
#pragma unroll
        for (int s = 0; s < NSIG; ++s)
#pragma unroll
            for (int r = 0; r < 4; ++r) {
                const float dd = dacc[s][r];
                const float inv = 1.0f / fmaxf(dd, 1e-6f);
#pragma unroll
                for (int h = 0; h < 2; ++h)
                    o0[(q * 4 + r) * (NSIG * CC) + s * CC + h * 16 + cl] = acc[s][h][r] * inv;
                if (cl == 0) o1[(q * 4 + r) * NSIG + s] = dd;
            }
    }
}

// ---- reduce: sum partials over n-chunks, divide, write final outputs ----
__global__ __launch_bounds__(128) void gsc_reduce_kernel(
    const float* __restrict__ partial, float* __restrict__ out0,
    float* __restrict__ out1, int nchunk)
{
    const size_t bg = blockIdx.x;
    const int v = threadIdx.x;   // 0..127 -> (s = v>>5, c = v&31)
    const int s = v >> 5;
    float num = 0.0f, dn = 0.0f;
    for (int nc = 0; nc < nchunk; ++nc) {
        const float* p = partial + ((size_t)nc * BB * GG + bg) * PVALS;
        num += p[v];
        dn  += p[128 + s];
    }
    out0[bg * 128 + v] = num / fmaxf(dn, 1e-6f);
    if (v < NSIG) {
        float d = 0.0f;
        for (int nc = 0; nc < nchunk; ++nc)
            d += partial[((size_t)nc * BB * GG + bg) * PVALS + 128 + v];
        out1[bg * NSIG + v] = d;
    }
}

extern "C" void kernel_launch(void* const* d_in, const int* in_sizes, int n_in,
                              void* d_out, int out_size, void* d_ws, size_t ws_size,
                              hipStream_t stream) {
    const float* px = (const float*)d_in[0];  // [B,N]
    const float* pf = (const float*)d_in[1];  // [B,N,C]
    const float* pm = (const float*)d_in[2];  // [B,N]
    const float* gx = (const float*)d_in[3];  // [G]
    float* out0 = (float*)d_out;                          // [B,G,4*C]
    float* out1 = out0 + (size_t)BB * GG * NSIG * CC;     // [B,G,4]

    const size_t fragWords = (size_t)BB * 256 * 256;   // 1 MB
    const size_t maskWords = (size_t)BB * NN / 2;      // 32 KB
    unsigned* fragw = (unsigned*)d_ws;
    unsigned* maskw = fragw + fragWords;
    float* partial  = (float*)(maskw + maskWords);
    const size_t used  = (fragWords + maskWords) * 4;
    const size_t avail = ws_size > used ? ws_size - used : 0;
    const size_t per   = (size_t)BB * GG * PVALS * sizeof(float);

    int nchunk = 1, direct = 1;
    if (8 * per <= avail)      { nchunk = 8; direct = 0; }
    else if (4 * per <= avail) { nchunk = 4; direct = 0; }
    else if (2 * per <= avail) { nchunk = 2; direct = 0; }
    else if (per <= avail)     { nchunk = 1; direct = 0; }

    gsc_prep_kernel<<<dim3(BB * (NN / 2) * CC / 256), dim3(256), 0, stream>>>(
        pf, pm, fragw, maskw);
    gsc_mfma_kernel<<<dim3(BB * (GG / 64) * nchunk), dim3(256), 0, stream>>>(
        px, fragw, maskw, gx, partial, out0, out1, nchunk, direct);
    if (!direct)
        gsc_reduce_kernel<<<dim3(BB * GG), dim3(128), 0, stream>>>(
            partial, out0, out1, nchunk);
}